// Round 12
// baseline (328.947 us; speedup 1.0000x reference)
//
#include <hip/hip_runtime.h>
#include <hip/hip_bf16.h>
#include <stdint.h>
#include <type_traits>

typedef __bf16 bf16;
typedef __bf16 bf16x8 __attribute__((ext_vector_type(8)));
typedef __bf16 bf16x4 __attribute__((ext_vector_type(4)));
typedef float f32x4 __attribute__((ext_vector_type(4)));

#define GLOAD_LDS16(gptr, lptr)                                                        \
  __builtin_amdgcn_global_load_lds((const __attribute__((address_space(1))) void*)(gptr), \
                                   (__attribute__((address_space(3))) void*)(lptr), 16, 0, 0)

// ---------------- weight cast fp32 -> bf16 ----------------
__global__ __launch_bounds__(256) void cast_f2b(const float* __restrict__ in,
                                                bf16* __restrict__ out, int n) {
  int i = (blockIdx.x * 256 + threadIdx.x) * 4;
  if (i >= n) return;
  const float4 v = *(const float4*)(in + i);
  bf16x4 o;
  o[0] = (bf16)v.x; o[1] = (bf16)v.y; o[2] = (bf16)v.z; o[3] = (bf16)v.w;
  *(bf16x4*)(out + i) = o;
}

__global__ __launch_bounds__(256) void zero_k(float* __restrict__ p, int n) {
  int i = blockIdx.x * 256 + threadIdx.x;
  if (i < n) p[i] = 0.f;
}

// ---------------- prep: cast+transpose x -> xbT[n][c], 2x2 maxpool -> pxT[m][c] ----
__global__ __launch_bounds__(256) void prep_kernel(const float* __restrict__ x,
                                                   bf16* __restrict__ xbT,
                                                   bf16* __restrict__ pxT) {
  const int b = blockIdx.y;
  x   += (size_t)b * 1024 * 4096;
  xbT += (size_t)b * 4096 * 1024;
  pxT += (size_t)b * 1024 * 1024;
  const int bid = blockIdx.x;
  const int h0 = bid & 31, ct = bid >> 5;
  const int tid = threadIdx.x;
  __shared__ float tile[32][129];
  const float* xs = x + (size_t)(ct * 32) * 4096 + h0 * 128;
#pragma unroll
  for (int e = 0; e < 16; ++e) {
    int idx = e * 256 + tid;
    int c = idx >> 7, n = idx & 127;
    tile[c][n] = xs[(size_t)c * 4096 + n];
  }
  __syncthreads();
  bf16* xo = xbT + (size_t)(h0 * 128) * 1024 + ct * 32;
#pragma unroll
  for (int e = 0; e < 16; ++e) {
    int idx = e * 256 + tid;
    int n = idx >> 5, c = idx & 31;
    xo[(size_t)n * 1024 + c] = (bf16)tile[c][n];
  }
  bf16* po = pxT + (size_t)(h0 * 32) * 1024 + ct * 32;
#pragma unroll
  for (int e = 0; e < 4; ++e) {
    int idx = e * 256 + tid;
    int m = idx >> 5, c = idx & 31;
    float v = fmaxf(fmaxf(tile[c][2 * m], tile[c][2 * m + 1]),
                    fmaxf(tile[c][64 + 2 * m], tile[c][64 + 2 * m + 1]));
    po[(size_t)m * 1024 + c] = (bf16)v;
  }
}

// ======== 128x256-tile GEMM, ring-3 counted-vmcnt, XCD-chunked 1D grid ========
// K-loop identical to R11 (race-clean: stage issued AFTER the body barrier).
// NEW: coalesced LDS-transposed epilogue — acc is dumped (one 64-row half per
// pass) into a padded fp32 [64][260] buffer reusing the staging LDS, then all
// 512 threads stream it out in 128B-contiguous segments (fixes the 64B/32B
// fragment-scatter granularity that capped G6 at ~2.4-3.6 TB/s effective).
// EPI: 1 bf16 (acc+bias[col])*scale ; 4 fp32 acc+bias[row]+resid ;
//      5 bf16 exp(acc) + atomic row-sums into rs_out ; 7 bf16 acc/bias[z*4096+row]
template <int EPI>
__global__ __launch_bounds__(512, 4) void gemm256(
    const bf16* __restrict__ A, long long sA, int lda,
    const bf16* __restrict__ B, long long sB, int ldb,
    void* __restrict__ Cv, long long sC, int ldc, int K,
    const float* __restrict__ bias,
    const float* __restrict__ resid, long long sResid, float scale,
    float* __restrict__ rs_out, int gx, int gy) {
  // ---- XCD-chunked bijective swizzle (nwg % 8 == 0 for all our launches) ----
  const int nwg = gridDim.x;
  const int flat = blockIdx.x;
  const int swz = (flat & 7) * (nwg >> 3) + (flat >> 3);
  const int bx = swz % gx;
  const int tmp = swz / gx;
  const int by = tmp % gy;
  const int z = tmp / gy;

  A += (size_t)z * sA;
  B += (size_t)z * sB;
  const int tid = threadIdx.x;
  const int w = tid >> 6, lane = tid & 63;
  const int r16 = lane & 15, q4 = lane >> 4;
  const int wm = w >> 2, wn = w & 3;
  const long long tileM = (long long)bx * 128;
  const long long tileN = (long long)by * 256;

  // 72KB pool: K-loop = As ring-3 (24KB) + Bs ring-3 (48KB); epilogue reuses
  // it as fp32 ep[64][260] (66.5KB).
  __shared__ __align__(16) char smem[73728];
  bf16* AsBase = (bf16*)smem;             // As[sl] = AsBase + sl*4096
  bf16* BsBase = (bf16*)(smem + 24576);   // Bs[sl] = BsBase + sl*8192
  float* ep = (float*)smem;
  const int EROW = 260;

  f32x4 acc[4][4] = {};

  // staging: thread covers (row = tid>>2, 16B-slot = tid&3); B adds row+128.
  const int srow = tid >> 2;
  const int skb  = (tid & 3) ^ ((srow >> 1) & 3);   // inverse swizzle on source
  const char* Ag = (const char*)A + ((size_t)(tileM + srow) * lda + skb * 8) * 2;
  const char* Bg = (const char*)B + ((size_t)(tileN + srow) * ldb + skb * 8) * 2;
  const size_t b128 = (size_t)128 * ldb * 2;   // ((r+128)>>1)&3 == (r>>1)&3

  auto stage = [&](int T) {  // 3 vm-ops
    const int sl = T % 3;
    GLOAD_LDS16(Ag + (size_t)T * 64, AsBase + sl * 4096 + w * 512);
    GLOAD_LDS16(Bg + (size_t)T * 64, BsBase + sl * 8192 + w * 512);
    GLOAD_LDS16(Bg + (size_t)T * 64 + b128, BsBase + sl * 8192 + 4096 + w * 512);
  };

  const int NT = K >> 5;
  stage(0);
  stage(1);

  for (int T = 0; T < NT; ++T) {
    // stage(T) complete; stage(T+1)'s 3 ops (if issued) stay in flight
    if (T + 1 < NT) asm volatile("s_waitcnt vmcnt(3)" ::: "memory");
    else            asm volatile("s_waitcnt vmcnt(0)" ::: "memory");
    __builtin_amdgcn_s_barrier();   // all waves' stage(T) writes now in LDS
    asm volatile("" ::: "memory");
    if (T + 2 < NT) stage(T + 2);   // writes slot (T-1)%3: its readers (body
                                    // T-1) all finished before this barrier

    const char* Asl = (const char*)(AsBase + (T % 3) * 4096);
    const char* Bsl = (const char*)(BsBase + (T % 3) * 8192);
    bf16x8 af[4], bf_[4];
#pragma unroll
    for (int mi = 0; mi < 4; ++mi) {
      const int row = wm * 64 + mi * 16 + r16;
      af[mi] = *(const bf16x8*)(Asl + row * 64 + ((q4 ^ ((row >> 1) & 3)) << 4));
    }
#pragma unroll
    for (int ni = 0; ni < 4; ++ni) {
      const int row = wn * 64 + ni * 16 + r16;
      bf_[ni] = *(const bf16x8*)(Bsl + row * 64 + ((q4 ^ ((row >> 1) & 3)) << 4));
    }
    __builtin_amdgcn_s_setprio(1);
#pragma unroll
    for (int mi = 0; mi < 4; ++mi)
#pragma unroll
      for (int ni = 0; ni < 4; ++ni)
        acc[mi][ni] = __builtin_amdgcn_mfma_f32_16x16x32_bf16(af[mi], bf_[ni], acc[mi][ni], 0, 0, 0);
    __builtin_amdgcn_s_setprio(0);
  }

  // ---- coalesced LDS-transposed epilogue ----
  __syncthreads();  // all K-loop LDS reads done before overwrite
  const int lrow = tid >> 3, c8 = tid & 7;   // 64 rows x 8 col-threads

#pragma unroll
  for (int h = 0; h < 2; ++h) {
    if (wm == h) {  // dump this half's acc: rows a*16+q4*4+r, cols wn*64+ni*16+r16
#pragma unroll
      for (int a = 0; a < 4; ++a)
#pragma unroll
        for (int ni = 0; ni < 4; ++ni) {
          const int lr0 = a * 16 + q4 * 4;
          const int lc = wn * 64 + ni * 16 + r16;
#pragma unroll
          for (int r = 0; r < 4; ++r)
            ep[(lr0 + r) * EROW + lc] = acc[a][ni][r];
        }
    }
    __syncthreads();
    const int grow = (int)tileM + h * 64 + lrow;

    if constexpr (EPI == 4) {
      float* C = (float*)Cv + (size_t)z * sC;
      const float* rz = resid + (size_t)z * sResid;
      const float bv = bias[grow];
#pragma unroll
      for (int j = 0; j < 8; ++j) {
        const int col = c8 * 4 + j * 32;  // 8 threads/row -> 128B contiguous
        float4 v = *(const float4*)&ep[lrow * EROW + col];
        const float4 rv = *(const float4*)&rz[(size_t)grow * ldc + (int)tileN + col];
        v.x += bv + rv.x; v.y += bv + rv.y; v.z += bv + rv.z; v.w += bv + rv.w;
        *(float4*)&C[(size_t)grow * ldc + (int)tileN + col] = v;
      }
    } else if constexpr (EPI == 5) {
      bf16* C = (bf16*)Cv + (size_t)z * sC;
      float* rsp = rs_out + (size_t)z * 4096;
      float s = 0.f;
#pragma unroll
      for (int j = 0; j < 4; ++j) {
        const int col = c8 * 8 + j * 64;  // 8 threads x 16B -> 128B contiguous
        const float4 lo = *(const float4*)&ep[lrow * EROW + col];
        const float4 hi = *(const float4*)&ep[lrow * EROW + col + 4];
        bf16x8 o;
        float e0 = __expf(lo.x), e1 = __expf(lo.y), e2 = __expf(lo.z), e3 = __expf(lo.w);
        float e4 = __expf(hi.x), e5 = __expf(hi.y), e6 = __expf(hi.z), e7 = __expf(hi.w);
        s += e0 + e1 + e2 + e3 + e4 + e5 + e6 + e7;
        o[0] = (bf16)e0; o[1] = (bf16)e1; o[2] = (bf16)e2; o[3] = (bf16)e3;
        o[4] = (bf16)e4; o[5] = (bf16)e5; o[6] = (bf16)e6; o[7] = (bf16)e7;
        *(bf16x8*)&C[(size_t)grow * ldc + (int)tileN + col] = o;
      }
      s += __shfl_xor(s, 1);
      s += __shfl_xor(s, 2);
      s += __shfl_xor(s, 4);
      if (c8 == 0) atomicAdd(&rsp[grow], s);
    } else if constexpr (EPI == 7) {
      bf16* C = (bf16*)Cv + (size_t)z * sC;
      const float inv = 1.0f / (bias + (size_t)z * 4096)[grow];
#pragma unroll
      for (int j = 0; j < 4; ++j) {
        const int col = c8 * 8 + j * 64;
        const float4 lo = *(const float4*)&ep[lrow * EROW + col];
        const float4 hi = *(const float4*)&ep[lrow * EROW + col + 4];
        bf16x8 o;
        o[0] = (bf16)(lo.x * inv); o[1] = (bf16)(lo.y * inv);
        o[2] = (bf16)(lo.z * inv); o[3] = (bf16)(lo.w * inv);
        o[4] = (bf16)(hi.x * inv); o[5] = (bf16)(hi.y * inv);
        o[6] = (bf16)(hi.z * inv); o[7] = (bf16)(hi.w * inv);
        *(bf16x8*)&C[(size_t)grow * ldc + (int)tileN + col] = o;
      }
    } else {  // EPI == 1
      bf16* C = (bf16*)Cv + (size_t)z * sC;
#pragma unroll
      for (int j = 0; j < 4; ++j) {
        const int col = c8 * 8 + j * 64;
        const float4 lo = *(const float4*)&ep[lrow * EROW + col];
        const float4 hi = *(const float4*)&ep[lrow * EROW + col + 4];
        const float4 b0 = *(const float4*)&bias[(int)tileN + col];
        const float4 b1 = *(const float4*)&bias[(int)tileN + col + 4];
        bf16x8 o;
        o[0] = (bf16)((lo.x + b0.x) * scale); o[1] = (bf16)((lo.y + b0.y) * scale);
        o[2] = (bf16)((lo.z + b0.z) * scale); o[3] = (bf16)((lo.w + b0.w) * scale);
        o[4] = (bf16)((hi.x + b1.x) * scale); o[5] = (bf16)((hi.y + b1.y) * scale);
        o[6] = (bf16)((hi.z + b1.z) * scale); o[7] = (bf16)((hi.w + b1.w) * scale);
        *(bf16x8*)&C[(size_t)grow * ldc + (int)tileN + col] = o;
      }
    }
    __syncthreads();  // read pass done before next dump overwrites
  }
}

// ---------------- 128^2 bt-GEMM (kept for small shapes G2/G3) ----------------
// EPI: 1 bf16 (acc + bias[col]) * scale; 2 bf16 + bias[row]
template <int EPI>
__global__ __launch_bounds__(256) void gemm_bt(
    const bf16* __restrict__ A, long long sA, int lda,
    const bf16* __restrict__ B, long long sB, int ldb,
    void* __restrict__ Cv, long long sC, int ldc, int K,
    const float* __restrict__ bias, float scale) {
  const int z = blockIdx.z;
  A += (size_t)z * sA;
  B += (size_t)z * sB;
  const int tid = threadIdx.x;
  const int w = tid >> 6, lane = tid & 63;
  const int r16 = lane & 15, q4 = lane >> 4;
  const long long tileM = (long long)blockIdx.x * 128;
  const long long tileN = (long long)blockIdx.y * 128;

  __shared__ bf16 As[2][128 * 32];
  __shared__ bf16 Bs[2][128 * 32];

  f32x4 acc[4][4] = {};

  const int srow = tid >> 2;
  const int soff = (tid & 3) * 16;
  const char* Ag0 = (const char*)A + ((size_t)(tileM + srow) * lda) * 2 + soff;
  const char* Bg0 = (const char*)B + ((size_t)(tileN + srow) * ldb) * 2 + soff;
  const size_t arow64 = (size_t)64 * lda * 2;
  const size_t brow64 = (size_t)64 * ldb * 2;

  auto stage = [&](int buf, int k0) {
    const char* a = Ag0 + (size_t)k0 * 2;
    const char* b = Bg0 + (size_t)k0 * 2;
    bf16* al = &As[buf][w * 512];
    bf16* bl = &Bs[buf][w * 512];
    GLOAD_LDS16(a, al);
    GLOAD_LDS16(a + arow64, al + 2048);
    GLOAD_LDS16(b, bl);
    GLOAD_LDS16(b + brow64, bl + 2048);
  };

  const int wr = (w >> 1) * 64, wc = (w & 1) * 64;
  const int nt = K >> 5;
  stage(0, 0);
  __syncthreads();
  int cur = 0;
  for (int t = 0; t < nt; ++t) {
    if (t + 1 < nt) stage(cur ^ 1, (t + 1) * 32);
    bf16x8 af[4], bfv[4];
#pragma unroll
    for (int f = 0; f < 4; ++f) {
      af[f]  = *(const bf16x8*)&As[cur][(wr + f * 16 + r16) * 32 + q4 * 8];
      bfv[f] = *(const bf16x8*)&Bs[cur][(wc + f * 16 + r16) * 32 + q4 * 8];
    }
#pragma unroll
    for (int i = 0; i < 4; ++i)
#pragma unroll
      for (int j = 0; j < 4; ++j)
        acc[i][j] = __builtin_amdgcn_mfma_f32_16x16x32_bf16(af[i], bfv[j], acc[i][j], 0, 0, 0);
    __syncthreads();
    cur ^= 1;
  }

  bf16* C = (bf16*)Cv + (size_t)z * sC;
#pragma unroll
  for (int i = 0; i < 4; ++i) {
    const int row0 = (int)tileM + wr + i * 16 + q4 * 4;
#pragma unroll
    for (int j = 0; j < 4; ++j) {
      const int col = (int)tileN + wc + j * 16 + r16;
      float badd = 0.f;
      if constexpr (EPI == 1) badd = bias[col];
#pragma unroll
      for (int r = 0; r < 4; ++r) {
        float v = acc[i][j][r];
        if constexpr (EPI == 1) v = (v + badd) * scale;
        if constexpr (EPI == 2) v += bias[row0 + r];
        C[(size_t)(row0 + r) * ldc + col] = (bf16)v;
      }
    }
  }
}

// ---------------- launch ----------------
extern "C" void kernel_launch(void* const* d_in, const int* in_sizes, int n_in,
                              void* d_out, int out_size, void* d_ws, size_t ws_size,
                              hipStream_t stream) {
  const float* x  = (const float*)d_in[0];
  const float* Wt = (const float*)d_in[1];
  const float* bt = (const float*)d_in[2];
  const float* Wp = (const float*)d_in[3];
  const float* bp = (const float*)d_in[4];
  const float* Wg = (const float*)d_in[5];
  const float* bg = (const float*)d_in[6];
  const float* Wo = (const float*)d_in[7];
  const float* bo = (const float*)d_in[8];
  float* out = (float*)d_out;

  const size_t MB = 1024ull * 1024ull;
  char* ws = (char*)d_ws;
  bf16* WtB = (bf16*)(ws + 0 * MB);
  bf16* WpB = (bf16*)(ws + 1 * MB);
  bf16* WgB = (bf16*)(ws + 2 * MB);
  bf16* WoB = (bf16*)(ws + 3 * MB);

  cast_f2b<<<512, 256, 0, stream>>>(Wt, WtB, 512 * 1024);
  cast_f2b<<<512, 256, 0, stream>>>(Wp, WpB, 512 * 1024);
  cast_f2b<<<512, 256, 0, stream>>>(Wg, WgB, 512 * 1024);
  cast_f2b<<<512, 256, 0, stream>>>(Wo, WoB, 1024 * 512);

  const float SCALE = 0.044194173824159216f;  // 512^-0.5, folded into theta

  // gemm256 launcher: 1D grid (gx*gy*gz blocks), dims passed for decomposition
  auto g256 = [&](auto epi_tag, int gx, int gy, int gz,
                  const bf16* A, long long sA, int lda,
                  const bf16* B, long long sB, int ldb,
                  void* Cv, long long sC, int ldc, int K,
                  const float* bias, const float* resid, long long sResid,
                  float scale, float* rs_out) {
    constexpr int EPI = decltype(epi_tag)::value;
    gemm256<EPI><<<gx * gy * gz, 512, 0, stream>>>(A, sA, lda, B, sB, ldb,
                                                   Cv, sC, ldc, K, bias,
                                                   resid, sResid, scale, rs_out,
                                                   gx, gy);
  };
  using E1 = std::integral_constant<int, 1>;
  using E4 = std::integral_constant<int, 4>;
  using E5 = std::integral_constant<int, 5>;
  using E7 = std::integral_constant<int, 7>;

  auto run_g6 = [&](int nb, int b0, bf16* tT) {
    g256(E4{}, 8, 16, nb, WoB, 0, 512, tT, 4096ll * 512, 512,
         out + (size_t)b0 * 1024 * 4096, 1024ll * 4096, 4096, 512,
         bo, x + (size_t)b0 * 1024 * 4096, 1024ll * 4096, 1.f, nullptr);
  };

  if (ws_size >= 164 * MB) {
    bf16* pxT    = (bf16*)(ws + 4 * MB);     // 16MB
    bf16* phiT   = (bf16*)(ws + 20 * MB);    // 8MB
    bf16* g      = (bf16*)(ws + 28 * MB);    // 8MB
    bf16* thetaT = (bf16*)(ws + 36 * MB);    // 32MB
    bf16* tT     = (bf16*)(ws + 68 * MB);    // 32MB
    bf16* xbT    = (bf16*)(ws + 100 * MB);   // 64MB (staging only; no aliasing)
    bf16*  Pt   = (bf16*)d_out;                       // 64MB scratch in d_out
    float* rsum = (float*)((char*)d_out + 80 * MB);   // 128KB scratch in d_out

    prep_kernel<<<dim3(1024, 8), 256, 0, stream>>>(x, xbT, pxT);
    g256(E1{}, 32, 2, 8, xbT, 4096ll * 1024, 1024, WtB, 0, 1024,
         thetaT, 4096ll * 512, 512, 1024, bt, nullptr, 0, SCALE, nullptr);
    gemm_bt<1><<<dim3(8, 4, 8), 256, 0, stream>>>(pxT, 1024ll * 1024, 1024, WpB, 0, 1024,
                                                  phiT, 1024ll * 512, 512, 1024, bp, 1.f);
    gemm_bt<2><<<dim3(4, 8, 8), 256, 0, stream>>>(WgB, 0, 1024, pxT, 1024ll * 1024, 1024,
                                                  g, 512ll * 1024, 1024, 1024, bg, 1.f);
    zero_k<<<128, 256, 0, stream>>>(rsum, 32768);
    g256(E5{}, 32, 4, 8, thetaT, 4096ll * 512, 512, phiT, 1024ll * 512, 512,
         Pt, 4096ll * 1024, 1024, 512, nullptr, nullptr, 0, 1.f, rsum);
    g256(E7{}, 32, 2, 8, Pt, 4096ll * 1024, 1024, g, 512ll * 1024, 1024,
         tT, 4096ll * 512, 512, 1024, rsum, nullptr, 0, 1.f, nullptr);
    run_g6(8, 0, tT);
  } else if (ws_size >= 108 * MB) {
    bf16* pxT    = (bf16*)(ws + 4 * MB);
    bf16* phiT   = (bf16*)(ws + 20 * MB);
    bf16* g      = (bf16*)(ws + 28 * MB);
    bf16* thetaT = (bf16*)(ws + 36 * MB);
    bf16* tT     = (bf16*)(ws + 68 * MB);
    bf16* xbT    = (bf16*)(ws + 100 * MB);   // 8MB per-batch staging
    float* rsum = (float*)((char*)d_out + 80 * MB);
    for (int b = 0; b < 8; ++b) {
      prep_kernel<<<dim3(1024, 1), 256, 0, stream>>>(x + (size_t)b * 1024 * 4096, xbT,
                                                     pxT + (size_t)b * 1024 * 1024);
      g256(E1{}, 32, 2, 1, xbT, 0, 1024, WtB, 0, 1024,
           thetaT + (size_t)b * 4096 * 512, 0, 512, 1024, bt, nullptr, 0, SCALE, nullptr);
    }
    gemm_bt<1><<<dim3(8, 4, 8), 256, 0, stream>>>(pxT, 1024ll * 1024, 1024, WpB, 0, 1024,
                                                  phiT, 1024ll * 512, 512, 1024, bp, 1.f);
    gemm_bt<2><<<dim3(4, 8, 8), 256, 0, stream>>>(WgB, 0, 1024, pxT, 1024ll * 1024, 1024,
                                                  g, 512ll * 1024, 1024, 1024, bg, 1.f);
    for (int b = 0; b < 8; ++b) {
      bf16* Ptb = (bf16*)d_out + (size_t)b * 4096 * 1024;
      zero_k<<<16, 256, 0, stream>>>(rsum + (size_t)b * 4096, 4096);
      g256(E5{}, 32, 4, 1, thetaT + (size_t)b * 4096 * 512, 0, 512,
           phiT + (size_t)b * 1024 * 512, 0, 512,
           Ptb, 0, 1024, 512, nullptr, nullptr, 0, 1.f, rsum + (size_t)b * 4096);
      g256(E7{}, 32, 2, 1, Ptb, 0, 1024, g + (size_t)b * 512 * 1024, 0, 1024,
           tT + (size_t)b * 4096 * 512, 0, 512, 1024,
           rsum + (size_t)b * 4096, nullptr, 0, 1.f, nullptr);
    }
    run_g6(8, 0, tT);
  } else {
    float* rsum  = (float*)(ws + 4 * MB);    // 16KB
    bf16* pxT    = (bf16*)(ws + 5 * MB);     // 2MB
    bf16* phiT   = (bf16*)(ws + 7 * MB);     // 1MB
    bf16* g      = (bf16*)(ws + 8 * MB);     // 1MB
    bf16* thetaT = (bf16*)(ws + 9 * MB);     // 4MB
    bf16* tT     = (bf16*)(ws + 13 * MB);    // 4MB
    bf16* Pt     = (bf16*)(ws + 17 * MB);    // 8MB
    bf16* xbT    = (bf16*)(ws + 25 * MB);    // 8MB -> 33MB total
    for (int b = 0; b < 8; ++b) {
      prep_kernel<<<dim3(1024, 1), 256, 0, stream>>>(x + (size_t)b * 1024 * 4096, xbT, pxT);
      g256(E1{}, 32, 2, 1, xbT, 0, 1024, WtB, 0, 1024,
           thetaT, 0, 512, 1024, bt, nullptr, 0, SCALE, nullptr);
      gemm_bt<1><<<dim3(8, 4, 1), 256, 0, stream>>>(pxT, 0, 1024, WpB, 0, 1024,
                                                    phiT, 0, 512, 1024, bp, 1.f);
      gemm_bt<2><<<dim3(4, 8, 1), 256, 0, stream>>>(WgB, 0, 1024, pxT, 0, 1024,
                                                    g, 0, 1024, 1024, bg, 1.f);
      zero_k<<<16, 256, 0, stream>>>(rsum, 4096);
      g256(E5{}, 32, 4, 1, thetaT, 0, 512, phiT, 0, 512,
           Pt, 0, 1024, 512, nullptr, nullptr, 0, 1.f, rsum);
      g256(E7{}, 32, 2, 1, Pt, 0, 1024, g, 0, 1024,
           tT, 0, 512, 1024, rsum, nullptr, 0, 1.f, nullptr);
      run_g6(1, b, tT);
    }
  }
}

// Round 13
// 322.229 us; speedup vs baseline: 1.0209x; 1.0209x over previous
//
#include <hip/hip_runtime.h>
#include <hip/hip_bf16.h>
#include <stdint.h>

typedef __bf16 bf16;
typedef __bf16 bf16x8 __attribute__((ext_vector_type(8)));
typedef __bf16 bf16x4 __attribute__((ext_vector_type(4)));
typedef float f32x4 __attribute__((ext_vector_type(4)));

#define GLOAD_LDS16(gptr, lptr)                                                        \
  __builtin_amdgcn_global_load_lds((const __attribute__((address_space(1))) void*)(gptr), \
                                   (__attribute__((address_space(3))) void*)(lptr), 16, 0, 0)

// ---------------- weight cast fp32 -> bf16 ----------------
__global__ __launch_bounds__(256) void cast_f2b(const float* __restrict__ in,
                                                bf16* __restrict__ out, int n) {
  int i = (blockIdx.x * 256 + threadIdx.x) * 4;
  if (i >= n) return;
  const float4 v = *(const float4*)(in + i);
  bf16x4 o;
  o[0] = (bf16)v.x; o[1] = (bf16)v.y; o[2] = (bf16)v.z; o[3] = (bf16)v.w;
  *(bf16x4*)(out + i) = o;
}

__global__ __launch_bounds__(256) void zero_k(float* __restrict__ p, int n) {
  int i = blockIdx.x * 256 + threadIdx.x;
  if (i < n) p[i] = 0.f;
}

// ---------------- prep: cast+transpose x -> xbT[n][c], 2x2 maxpool -> pxT[m][c] ----
__global__ __launch_bounds__(256) void prep_kernel(const float* __restrict__ x,
                                                   bf16* __restrict__ xbT,
                                                   bf16* __restrict__ pxT) {
  const int b = blockIdx.y;
  x   += (size_t)b * 1024 * 4096;
  xbT += (size_t)b * 4096 * 1024;
  pxT += (size_t)b * 1024 * 1024;
  const int bid = blockIdx.x;
  const int h0 = bid & 31, ct = bid >> 5;
  const int tid = threadIdx.x;
  __shared__ float tile[32][129];
  const float* xs = x + (size_t)(ct * 32) * 4096 + h0 * 128;
#pragma unroll
  for (int e = 0; e < 16; ++e) {
    int idx = e * 256 + tid;
    int c = idx >> 7, n = idx & 127;
    tile[c][n] = xs[(size_t)c * 4096 + n];
  }
  __syncthreads();
  bf16* xo = xbT + (size_t)(h0 * 128) * 1024 + ct * 32;
#pragma unroll
  for (int e = 0; e < 16; ++e) {
    int idx = e * 256 + tid;
    int n = idx >> 5, c = idx & 31;
    xo[(size_t)n * 1024 + c] = (bf16)tile[c][n];
  }
  bf16* po = pxT + (size_t)(h0 * 32) * 1024 + ct * 32;
#pragma unroll
  for (int e = 0; e < 4; ++e) {
    int idx = e * 256 + tid;
    int m = idx >> 5, c = idx & 31;
    float v = fmaxf(fmaxf(tile[c][2 * m], tile[c][2 * m + 1]),
                    fmaxf(tile[c][64 + 2 * m], tile[c][64 + 2 * m + 1]));
    po[(size_t)m * 1024 + c] = (bf16)v;
  }
}

// ======== 128x256-tile GEMM: C[MxN] = A[MxK] * B[NxK]^T  (R9 schedule) ========
// 8 waves (2M x 4N), per-wave 64x64 output. BK=32, ring-2 LDS (48KB).
// Body T: vmcnt(0) [stage T, 1-deep prefetch] -> s_barrier -> issue stage(T+1)
// -> 8 swizzled ds_read_b128 + 16 MFMA. Write/read hazards separated by the
// barrier (readers' ds_reads drained by compiler lgkm-waits pre-MFMA).
// LDS swizzle: 16B slot = kb ^ ((row>>1)&3), inverse applied on global src.
// EPI: 1 bf16 (acc+bias[col])*scale ; 4 fp32 acc+bias[row]+resid (NONTEMPORAL
//      resid load + out store: use-once fp32 streams bypass L2 retention) ;
//      5 bf16 exp(acc) + atomic row-sums into rs_out ; 7 bf16 acc/bias[z*4096+row]
template <int EPI>
__global__ __launch_bounds__(512, 4) void gemm256(
    const bf16* __restrict__ A, long long sA, int lda,
    const bf16* __restrict__ B, long long sB, int ldb,
    void* __restrict__ Cv, long long sC, int ldc, int K,
    const float* __restrict__ bias,
    const float* __restrict__ resid, long long sResid, float scale,
    float* __restrict__ rs_out) {
  const int z = blockIdx.z;
  A += (size_t)z * sA;
  B += (size_t)z * sB;
  const int tid = threadIdx.x;
  const int w = tid >> 6, lane = tid & 63;
  const int r16 = lane & 15, q4 = lane >> 4;
  const int wm = w >> 2, wn = w & 3;
  const long long tileM = (long long)blockIdx.x * 128;
  const long long tileN = (long long)blockIdx.y * 256;

  __shared__ bf16 As[2][4096];  // 16KB: [slot][128 rows][32 k], swizzled 16B lanes
  __shared__ bf16 Bs[2][8192];  // 32KB: [slot][256 rows][32 k]

  f32x4 acc[4][4] = {};

  // staging: thread covers (row = tid>>2, 16B-slot = tid&3); B adds row+128.
  const int srow = tid >> 2;
  const int skb  = (tid & 3) ^ ((srow >> 1) & 3);   // inverse swizzle on source
  const char* Ag = (const char*)A + ((size_t)(tileM + srow) * lda + skb * 8) * 2;
  const char* Bg = (const char*)B + ((size_t)(tileN + srow) * ldb + skb * 8) * 2;
  const size_t b128 = (size_t)128 * ldb * 2;   // ((r+128)>>1)&3 == (r>>1)&3

  auto stage = [&](int T) {  // 3 vm-ops
    const int sl = T & 1;
    GLOAD_LDS16(Ag + (size_t)T * 64, &As[sl][w * 512]);
    GLOAD_LDS16(Bg + (size_t)T * 64, &Bs[sl][w * 512]);
    GLOAD_LDS16(Bg + (size_t)T * 64 + b128, &Bs[sl][4096 + w * 512]);
  };

  stage(0);
  const int NT = K >> 5;

  for (int T = 0; T < NT; ++T) {
    asm volatile("s_waitcnt vmcnt(0)" ::: "memory");  // stage(T) done (own ops)
    __builtin_amdgcn_s_barrier();                     // -> all waves' stage(T) done
    asm volatile("" ::: "memory");
    if (T + 1 < NT) stage(T + 1);                     // slot (T+1)&1: old readers
                                                      // finished before this barrier
    const char* Asl = (const char*)&As[T & 1][0];
    const char* Bsl = (const char*)&Bs[T & 1][0];
    bf16x8 af[4], bf_[4];
#pragma unroll
    for (int mi = 0; mi < 4; ++mi) {
      const int row = wm * 64 + mi * 16 + r16;
      af[mi] = *(const bf16x8*)(Asl + row * 64 + ((q4 ^ ((row >> 1) & 3)) << 4));
    }
#pragma unroll
    for (int ni = 0; ni < 4; ++ni) {
      const int row = wn * 64 + ni * 16 + r16;
      bf_[ni] = *(const bf16x8*)(Bsl + row * 64 + ((q4 ^ ((row >> 1) & 3)) << 4));
    }
    __builtin_amdgcn_s_setprio(1);
#pragma unroll
    for (int mi = 0; mi < 4; ++mi)
#pragma unroll
      for (int ni = 0; ni < 4; ++ni)
        acc[mi][ni] = __builtin_amdgcn_mfma_f32_16x16x32_bf16(af[mi], bf_[ni], acc[mi][ni], 0, 0, 0);
    __builtin_amdgcn_s_setprio(0);
  }

  if constexpr (EPI == 4) {
    float* C = (float*)Cv + (size_t)z * sC;
    const float* rz = resid + (size_t)z * sResid;
#pragma unroll
    for (int a = 0; a < 4; ++a) {
      const int row0 = (int)tileM + wm * 64 + a * 16 + q4 * 4;
#pragma unroll
      for (int ni = 0; ni < 4; ++ni) {
        const int col = (int)tileN + wn * 64 + ni * 16 + r16;
#pragma unroll
        for (int r = 0; r < 4; ++r) {
          const float rv = __builtin_nontemporal_load(
              &rz[(size_t)(row0 + r) * ldc + col]);
          const float vv = acc[a][ni][r] + bias[row0 + r] + rv;
          __builtin_nontemporal_store(vv, &C[(size_t)(row0 + r) * ldc + col]);
        }
      }
    }
  } else if constexpr (EPI == 5) {
    bf16* C = (bf16*)Cv + (size_t)z * sC;
    float* rsp = rs_out + (size_t)z * 4096;
#pragma unroll
    for (int a = 0; a < 4; ++a) {
      const int row0 = (int)tileM + wm * 64 + a * 16 + q4 * 4;
      float psum[4] = {0.f, 0.f, 0.f, 0.f};
#pragma unroll
      for (int ni = 0; ni < 4; ++ni) {
        const int col = (int)tileN + wn * 64 + ni * 16 + r16;
#pragma unroll
        for (int r = 0; r < 4; ++r) {
          float e = __expf(acc[a][ni][r]);
          psum[r] += e;
          C[(size_t)(row0 + r) * ldc + col] = (bf16)e;
        }
      }
#pragma unroll
      for (int r = 0; r < 4; ++r) {
        float v = psum[r];
        v += __shfl_xor(v, 1);
        v += __shfl_xor(v, 2);
        v += __shfl_xor(v, 4);
        v += __shfl_xor(v, 8);
        if (r16 == 0) atomicAdd(&rsp[row0 + r], v);
      }
    }
  } else if constexpr (EPI == 7) {
    bf16* C = (bf16*)Cv + (size_t)z * sC;
    const float* rsp = bias + (size_t)z * 4096;
#pragma unroll
    for (int a = 0; a < 4; ++a) {
      const int row0 = (int)tileM + wm * 64 + a * 16 + q4 * 4;
      float inv[4];
#pragma unroll
      for (int r = 0; r < 4; ++r) inv[r] = 1.0f / rsp[row0 + r];
#pragma unroll
      for (int ni = 0; ni < 4; ++ni) {
        const int col = (int)tileN + wn * 64 + ni * 16 + r16;
#pragma unroll
        for (int r = 0; r < 4; ++r)
          C[(size_t)(row0 + r) * ldc + col] = (bf16)(acc[a][ni][r] * inv[r]);
      }
    }
  } else {  // EPI == 1
    bf16* C = (bf16*)Cv + (size_t)z * sC;
#pragma unroll
    for (int a = 0; a < 4; ++a) {
      const int row0 = (int)tileM + wm * 64 + a * 16 + q4 * 4;
#pragma unroll
      for (int ni = 0; ni < 4; ++ni) {
        const int col = (int)tileN + wn * 64 + ni * 16 + r16;
        const float badd = bias[col];
#pragma unroll
        for (int r = 0; r < 4; ++r)
          C[(size_t)(row0 + r) * ldc + col] = (bf16)((acc[a][ni][r] + badd) * scale);
      }
    }
  }
}

// ---------------- 128^2 bt-GEMM (kept for small shapes G2/G3) ----------------
// EPI: 1 bf16 (acc + bias[col]) * scale; 2 bf16 + bias[row]
template <int EPI>
__global__ __launch_bounds__(256) void gemm_bt(
    const bf16* __restrict__ A, long long sA, int lda,
    const bf16* __restrict__ B, long long sB, int ldb,
    void* __restrict__ Cv, long long sC, int ldc, int K,
    const float* __restrict__ bias, float scale) {
  const int z = blockIdx.z;
  A += (size_t)z * sA;
  B += (size_t)z * sB;
  const int tid = threadIdx.x;
  const int w = tid >> 6, lane = tid & 63;
  const int r16 = lane & 15, q4 = lane >> 4;
  const long long tileM = (long long)blockIdx.x * 128;
  const long long tileN = (long long)blockIdx.y * 128;

  __shared__ bf16 As[2][128 * 32];
  __shared__ bf16 Bs[2][128 * 32];

  f32x4 acc[4][4] = {};

  const int srow = tid >> 2;
  const int soff = (tid & 3) * 16;
  const char* Ag0 = (const char*)A + ((size_t)(tileM + srow) * lda) * 2 + soff;
  const char* Bg0 = (const char*)B + ((size_t)(tileN + srow) * ldb) * 2 + soff;
  const size_t arow64 = (size_t)64 * lda * 2;
  const size_t brow64 = (size_t)64 * ldb * 2;

  auto stage = [&](int buf, int k0) {
    const char* a = Ag0 + (size_t)k0 * 2;
    const char* b = Bg0 + (size_t)k0 * 2;
    bf16* al = &As[buf][w * 512];
    bf16* bl = &Bs[buf][w * 512];
    GLOAD_LDS16(a, al);
    GLOAD_LDS16(a + arow64, al + 2048);
    GLOAD_LDS16(b, bl);
    GLOAD_LDS16(b + brow64, bl + 2048);
  };

  const int wr = (w >> 1) * 64, wc = (w & 1) * 64;
  const int nt = K >> 5;
  stage(0, 0);
  __syncthreads();
  int cur = 0;
  for (int t = 0; t < nt; ++t) {
    if (t + 1 < nt) stage(cur ^ 1, (t + 1) * 32);
    bf16x8 af[4], bfv[4];
#pragma unroll
    for (int f = 0; f < 4; ++f) {
      af[f]  = *(const bf16x8*)&As[cur][(wr + f * 16 + r16) * 32 + q4 * 8];
      bfv[f] = *(const bf16x8*)&Bs[cur][(wc + f * 16 + r16) * 32 + q4 * 8];
    }
#pragma unroll
    for (int i = 0; i < 4; ++i)
#pragma unroll
      for (int j = 0; j < 4; ++j)
        acc[i][j] = __builtin_amdgcn_mfma_f32_16x16x32_bf16(af[i], bfv[j], acc[i][j], 0, 0, 0);
    __syncthreads();
    cur ^= 1;
  }

  bf16* C = (bf16*)Cv + (size_t)z * sC;
#pragma unroll
  for (int i = 0; i < 4; ++i) {
    const int row0 = (int)tileM + wr + i * 16 + q4 * 4;
#pragma unroll
    for (int j = 0; j < 4; ++j) {
      const int col = (int)tileN + wc + j * 16 + r16;
      float badd = 0.f;
      if constexpr (EPI == 1) badd = bias[col];
#pragma unroll
      for (int r = 0; r < 4; ++r) {
        float v = acc[i][j][r];
        if constexpr (EPI == 1) v = (v + badd) * scale;
        if constexpr (EPI == 2) v += bias[row0 + r];
        C[(size_t)(row0 + r) * ldc + col] = (bf16)v;
      }
    }
  }
}

// ---------------- launch ----------------
extern "C" void kernel_launch(void* const* d_in, const int* in_sizes, int n_in,
                              void* d_out, int out_size, void* d_ws, size_t ws_size,
                              hipStream_t stream) {
  const float* x  = (const float*)d_in[0];
  const float* Wt = (const float*)d_in[1];
  const float* bt = (const float*)d_in[2];
  const float* Wp = (const float*)d_in[3];
  const float* bp = (const float*)d_in[4];
  const float* Wg = (const float*)d_in[5];
  const float* bg = (const float*)d_in[6];
  const float* Wo = (const float*)d_in[7];
  const float* bo = (const float*)d_in[8];
  float* out = (float*)d_out;

  const size_t MB = 1024ull * 1024ull;
  char* ws = (char*)d_ws;
  bf16* WtB = (bf16*)(ws + 0 * MB);
  bf16* WpB = (bf16*)(ws + 1 * MB);
  bf16* WgB = (bf16*)(ws + 2 * MB);
  bf16* WoB = (bf16*)(ws + 3 * MB);

  cast_f2b<<<512, 256, 0, stream>>>(Wt, WtB, 512 * 1024);
  cast_f2b<<<512, 256, 0, stream>>>(Wp, WpB, 512 * 1024);
  cast_f2b<<<512, 256, 0, stream>>>(Wg, WgB, 512 * 1024);
  cast_f2b<<<512, 256, 0, stream>>>(Wo, WoB, 1024 * 512);

  const float SCALE = 0.044194173824159216f;  // 512^-0.5, folded into theta

  auto run_g6 = [&](int nb, int b0, bf16* tT) {
    gemm256<4><<<dim3(8, 16, nb), 512, 0, stream>>>(WoB, 0, 512, tT, 4096ll * 512, 512,
                                                    out + (size_t)b0 * 1024 * 4096,
                                                    1024ll * 4096, 4096, 512,
                                                    bo, x + (size_t)b0 * 1024 * 4096,
                                                    1024ll * 4096, 1.f, nullptr);
  };

  if (ws_size >= 164 * MB) {
    bf16* pxT    = (bf16*)(ws + 4 * MB);     // 16MB
    bf16* phiT   = (bf16*)(ws + 20 * MB);    // 8MB
    bf16* g      = (bf16*)(ws + 28 * MB);    // 8MB
    bf16* thetaT = (bf16*)(ws + 36 * MB);    // 32MB
    bf16* tT     = (bf16*)(ws + 68 * MB);    // 32MB
    bf16* xbT    = (bf16*)(ws + 100 * MB);   // 64MB (staging only; no aliasing)
    bf16*  Pt   = (bf16*)d_out;                       // 64MB scratch in d_out
    float* rsum = (float*)((char*)d_out + 80 * MB);   // 128KB scratch in d_out

    prep_kernel<<<dim3(1024, 8), 256, 0, stream>>>(x, xbT, pxT);
    gemm256<1><<<dim3(32, 2, 8), 512, 0, stream>>>(xbT, 4096ll * 1024, 1024, WtB, 0, 1024,
                                                   thetaT, 4096ll * 512, 512, 1024,
                                                   bt, nullptr, 0, SCALE, nullptr);
    gemm_bt<1><<<dim3(8, 4, 8), 256, 0, stream>>>(pxT, 1024ll * 1024, 1024, WpB, 0, 1024,
                                                  phiT, 1024ll * 512, 512, 1024, bp, 1.f);
    gemm_bt<2><<<dim3(4, 8, 8), 256, 0, stream>>>(WgB, 0, 1024, pxT, 1024ll * 1024, 1024,
                                                  g, 512ll * 1024, 1024, 1024, bg, 1.f);
    zero_k<<<128, 256, 0, stream>>>(rsum, 32768);
    gemm256<5><<<dim3(32, 4, 8), 512, 0, stream>>>(thetaT, 4096ll * 512, 512,
                                                   phiT, 1024ll * 512, 512,
                                                   Pt, 4096ll * 1024, 1024, 512,
                                                   nullptr, nullptr, 0, 1.f, rsum);
    gemm256<7><<<dim3(32, 2, 8), 512, 0, stream>>>(Pt, 4096ll * 1024, 1024,
                                                   g, 512ll * 1024, 1024,
                                                   tT, 4096ll * 512, 512, 1024,
                                                   rsum, nullptr, 0, 1.f, nullptr);
    run_g6(8, 0, tT);
  } else if (ws_size >= 108 * MB) {
    bf16* pxT    = (bf16*)(ws + 4 * MB);
    bf16* phiT   = (bf16*)(ws + 20 * MB);
    bf16* g      = (bf16*)(ws + 28 * MB);
    bf16* thetaT = (bf16*)(ws + 36 * MB);
    bf16* tT     = (bf16*)(ws + 68 * MB);
    bf16* xbT    = (bf16*)(ws + 100 * MB);   // 8MB per-batch staging
    float* rsum = (float*)((char*)d_out + 80 * MB);
    for (int b = 0; b < 8; ++b) {
      prep_kernel<<<dim3(1024, 1), 256, 0, stream>>>(x + (size_t)b * 1024 * 4096, xbT,
                                                     pxT + (size_t)b * 1024 * 1024);
      gemm256<1><<<dim3(32, 2, 1), 512, 0, stream>>>(xbT, 0, 1024, WtB, 0, 1024,
                                                     thetaT + (size_t)b * 4096 * 512, 0, 512,
                                                     1024, bt, nullptr, 0, SCALE, nullptr);
    }
    gemm_bt<1><<<dim3(8, 4, 8), 256, 0, stream>>>(pxT, 1024ll * 1024, 1024, WpB, 0, 1024,
                                                  phiT, 1024ll * 512, 512, 1024, bp, 1.f);
    gemm_bt<2><<<dim3(4, 8, 8), 256, 0, stream>>>(WgB, 0, 1024, pxT, 1024ll * 1024, 1024,
                                                  g, 512ll * 1024, 1024, 1024, bg, 1.f);
    for (int b = 0; b < 8; ++b) {
      bf16* Ptb = (bf16*)d_out + (size_t)b * 4096 * 1024;
      zero_k<<<16, 256, 0, stream>>>(rsum + (size_t)b * 4096, 4096);
      gemm256<5><<<dim3(32, 4, 1), 512, 0, stream>>>(thetaT + (size_t)b * 4096 * 512, 0, 512,
                                                     phiT + (size_t)b * 1024 * 512, 0, 512,
                                                     Ptb, 0, 1024, 512,
                                                     nullptr, nullptr, 0, 1.f,
                                                     rsum + (size_t)b * 4096);
      gemm256<7><<<dim3(32, 2, 1), 512, 0, stream>>>(Ptb, 0, 1024,
                                                     g + (size_t)b * 512 * 1024, 0, 1024,
                                                     tT + (size_t)b * 4096 * 512, 0, 512, 1024,
                                                     rsum + (size_t)b * 4096, nullptr, 0, 1.f,
                                                     nullptr);
    }
    run_g6(8, 0, tT);
  } else {
    float* rsum  = (float*)(ws + 4 * MB);    // 16KB
    bf16* pxT    = (bf16*)(ws + 5 * MB);     // 2MB
    bf16* phiT   = (bf16*)(ws + 7 * MB);     // 1MB
    bf16* g      = (bf16*)(ws + 8 * MB);     // 1MB
    bf16* thetaT = (bf16*)(ws + 9 * MB);     // 4MB
    bf16* tT     = (bf16*)(ws + 13 * MB);    // 4MB
    bf16* Pt     = (bf16*)(ws + 17 * MB);    // 8MB
    bf16* xbT    = (bf16*)(ws + 25 * MB);    // 8MB -> 33MB total
    for (int b = 0; b < 8; ++b) {
      prep_kernel<<<dim3(1024, 1), 256, 0, stream>>>(x + (size_t)b * 1024 * 4096, xbT, pxT);
      gemm256<1><<<dim3(32, 2, 1), 512, 0, stream>>>(xbT, 0, 1024, WtB, 0, 1024,
                                                     thetaT, 0, 512, 1024,
                                                     bt, nullptr, 0, SCALE, nullptr);
      gemm_bt<1><<<dim3(8, 4, 1), 256, 0, stream>>>(pxT, 0, 1024, WpB, 0, 1024,
                                                    phiT, 0, 512, 1024, bp, 1.f);
      gemm_bt<2><<<dim3(4, 8, 1), 256, 0, stream>>>(WgB, 0, 1024, pxT, 0, 1024,
                                                    g, 0, 1024, 1024, bg, 1.f);
      zero_k<<<16, 256, 0, stream>>>(rsum, 4096);
      gemm256<5><<<dim3(32, 4, 1), 512, 0, stream>>>(thetaT, 0, 512, phiT, 0, 512,
                                                     Pt, 0, 1024, 512,
                                                     nullptr, nullptr, 0, 1.f, rsum);
      gemm256<7><<<dim3(32, 2, 1), 512, 0, stream>>>(Pt, 0, 1024, g, 0, 1024,
                                                     tT, 0, 512, 1024,
                                                     rsum, nullptr, 0, 1.f, nullptr);
      run_g6(1, b, tT);
    }
  }
}